// Round 6
// baseline (54.044 us; speedup 1.0000x reference)
//
#include <hip/hip_runtime.h>
#include <hip/hip_bf16.h>
#include <math.h>

// v5: K-split wave pairs for 2x concurrency (16 waves/CU), 3 barriers total.
//  - 2048 blocks x 128 thr (2 waves). Block owns 16 batch rows.
//  - Layer 1 (K=784 padded to 832 = 26 tiles of 32): wave h does tiles
//    h*13..h*13+12 (uniform 13-tile pipelined loop), f32 partial reduction
//    via 8KB LDS + 1 barrier.
//  - Layer 2: N-split (wave h -> cols h*128..+127), h1 shared in LDS.
//  - Layer 3 + log_softmax: wave 0 only (8 MFMAs).
//  - Weights pre-packed to MFMA fragment order by prep_pack (d_ws), so all
//    B-loads are coalesced global_load_dwordx4 at base+lane*16 (L1/L2-hot).
//  - x: global->reg fp32, cvt_pk to bf16, B-frags + x ping-pong prefetched.
// LDS 12KB/block -> 8 blocks/CU; launch_bounds(128,4) -> VGPR cap 128.

#define TPB 128

// packed-weight layout (shorts): w1p [26kt][8nf][64lane][8]
#define NF1  208
#define W2P  106496            // = NF1*512;  w2p [4kt][16nf][64][8]
#define W3P  139264            // = W2P+64*512; w3p [8kt][64][8]
#define NFRAG_TOT 280
#define WTOT (NFRAG_TOT * 512)

typedef __attribute__((ext_vector_type(8))) short bf16x8;
typedef __attribute__((ext_vector_type(4))) float f32x4;

static __device__ inline short f2bf(float f) {
    union { float f; unsigned u; } v; v.f = f;
    unsigned r = v.u + 0x7fffu + ((v.u >> 16) & 1u);   // RNE
    return (short)(r >> 16);
}
static __device__ inline bf16x8 cvt8(float4 a, float4 b) {
    union { __hip_bfloat162 h2[4]; bf16x8 v; } u;
    u.h2[0] = __float22bfloat162_rn(make_float2(a.x, a.y));
    u.h2[1] = __float22bfloat162_rn(make_float2(a.z, a.w));
    u.h2[2] = __float22bfloat162_rn(make_float2(b.x, b.y));
    u.h2[3] = __float22bfloat162_rn(make_float2(b.z, b.w));
    return u.v;
}
static __device__ inline float4 ld4g(const float* p, bool ok) {
    return ok ? *reinterpret_cast<const float4*>(p) : make_float4(0.f,0.f,0.f,0.f);
}

__global__ void prep_pack(const float* __restrict__ w1,
                          const float* __restrict__ w2,
                          const float* __restrict__ w3,
                          short* __restrict__ wb) {
    const int tid = blockIdx.x * blockDim.x + threadIdx.x;   // one per (frag, lane)
    if (tid >= NFRAG_TOT * 64) return;
    const int fg = tid >> 6, lane = tid & 63;
    const int l15 = lane & 15, l4 = lane >> 4;
    float4 va = make_float4(0,0,0,0), vb = va;
    if (fg < NF1) {                       // w1: kt = fg>>3 (0..25), nf = fg&7
        const int kt = fg >> 3, nf = fg & 7;
        const int kg = kt * 32 + l4 * 8;
        if (kg + 8 <= 784) {
            const float* p = &w1[(size_t)(nf * 16 + l15) * 784 + kg];
            va = *(const float4*)p; vb = *(const float4*)(p + 4);
        }
    } else if (fg < NF1 + 64) {           // w2: 4 kt x 16 nf
        const int g = fg - NF1, kt = g >> 4, nf = g & 15;
        const float* p = &w2[(size_t)(nf * 16 + l15) * 128 + kt * 32 + l4 * 8];
        va = *(const float4*)p; vb = *(const float4*)(p + 4);
    } else {                              // w3: 8 kt, classes on l15 (>=10 zero)
        const int kt = fg - (NF1 + 64);
        if (l15 < 10) {
            const float* p = &w3[(size_t)l15 * 256 + kt * 32 + l4 * 8];
            va = *(const float4*)p; vb = *(const float4*)(p + 4);
        }
    }
    *(bf16x8*)&wb[(size_t)tid * 8] = cvt8(va, vb);
}

__global__ __launch_bounds__(TPB, 4) void mnist_v5(
    const float* __restrict__ x,    // [32768,784]
    const float* __restrict__ b1v,  // [128]
    const float* __restrict__ b2v,  // [256]
    const float* __restrict__ b3v,  // [10]
    const short* __restrict__ wb,   // packed bf16 weights
    float* __restrict__ out)        // [32768,10]
{
    __shared__ __align__(16) float s_red[16 * 128];  // 8KB region A: f32 partials, then h2 overlay
    __shared__ __align__(16) short s_h1[16 * 128];   // 4KB region B: h1 bf16 [16][128]
    short* const s_h2 = (short*)&s_red[0];           // [16][256] bf16 overlay

    const int t    = threadIdx.x;
    const int lane = t & 63;
    const int h    = t >> 6;         // K-half (L1) / N-half (L2)
    const int l15  = lane & 15;
    const int l4   = lane >> 4;
    const int r0   = blockIdx.x * 16;

    const float* xrow = &x[(size_t)(r0 + l15) * 784];
    const int kt0 = h * 13;

    // ================= Layer 1: 13 K-tiles of 32 per wave, full N=128 =========
    f32x4 acc1[8];
    #pragma unroll
    for (int nf = 0; nf < 8; ++nf) acc1[nf] = (f32x4){0.f,0.f,0.f,0.f};

    bf16x8 bA[8], bB[8];
    #pragma unroll
    for (int nf = 0; nf < 8; ++nf)
        bA[nf] = *(const bf16x8*)&wb[((size_t)(kt0 * 8 + nf)) * 512 + lane * 8];
    {
        const int kg = kt0 * 32 + l4 * 8;
        const bool ok = kg + 8 <= 784;
        float4 xc0 = ld4g(xrow + kg, ok), xc1 = ld4g(xrow + kg + 4, ok);

        for (int it = 0; it < 12; it += 2) {
            // prefetch tile kt0+it+1
            #pragma unroll
            for (int nf = 0; nf < 8; ++nf)
                bB[nf] = *(const bf16x8*)&wb[((size_t)((kt0 + it + 1) * 8 + nf)) * 512 + lane * 8];
            int kg2 = (kt0 + it + 1) * 32 + l4 * 8;
            bool ok2 = kg2 + 8 <= 784;
            float4 xn0 = ld4g(xrow + kg2, ok2), xn1 = ld4g(xrow + kg2 + 4, ok2);
            {
                const bf16x8 a = cvt8(xc0, xc1);
                #pragma unroll
                for (int nf = 0; nf < 8; ++nf)
                    acc1[nf] = __builtin_amdgcn_mfma_f32_16x16x32_bf16(a, bA[nf], acc1[nf], 0, 0, 0);
            }
            xc0 = xn0; xc1 = xn1;
            // prefetch tile kt0+it+2
            #pragma unroll
            for (int nf = 0; nf < 8; ++nf)
                bA[nf] = *(const bf16x8*)&wb[((size_t)((kt0 + it + 2) * 8 + nf)) * 512 + lane * 8];
            kg2 = (kt0 + it + 2) * 32 + l4 * 8;
            ok2 = kg2 + 8 <= 784;
            xn0 = ld4g(xrow + kg2, ok2); xn1 = ld4g(xrow + kg2 + 4, ok2);
            {
                const bf16x8 a = cvt8(xc0, xc1);
                #pragma unroll
                for (int nf = 0; nf < 8; ++nf)
                    acc1[nf] = __builtin_amdgcn_mfma_f32_16x16x32_bf16(a, bB[nf], acc1[nf], 0, 0, 0);
            }
            xc0 = xn0; xc1 = xn1;
        }
        {   // tail: tile kt0+12 (in bA)
            const bf16x8 a = cvt8(xc0, xc1);
            #pragma unroll
            for (int nf = 0; nf < 8; ++nf)
                acc1[nf] = __builtin_amdgcn_mfma_f32_16x16x32_bf16(a, bA[nf], acc1[nf], 0, 0, 0);
        }
    }

    // -------- pair reduction: h=1 writes partials (col-major f32), h=0 combines
    if (h) {
        #pragma unroll
        for (int nf = 0; nf < 8; ++nf)
            *(f32x4*)&s_red[(nf * 16 + l15) * 16 + l4 * 4] = acc1[nf];
    }
    __syncthreads();                              // barrier 1
    if (!h) {
        #pragma unroll
        for (int nf = 0; nf < 8; ++nf) {
            const int c = nf * 16 + l15;
            const f32x4 p = *(const f32x4*)&s_red[c * 16 + l4 * 4];
            const float bc = b1v[c];
            #pragma unroll
            for (int i = 0; i < 4; ++i) {
                const int r = l4 * 4 + i;
                const float v = fmaxf(acc1[nf][i] + p[i] + bc, 0.f);
                s_h1[r * 128 + (((c >> 3) ^ (r & 7)) << 3) + (c & 7)] = f2bf(v);
            }
        }
    }
    __syncthreads();                              // barrier 2: h1 ready, red dead

    // ================= Layer 2: full K=128, N-half per wave ===================
    bf16x8 a2[4];
    #pragma unroll
    for (int kk = 0; kk < 4; ++kk)
        a2[kk] = *(const bf16x8*)&s_h1[l15 * 128 + (((kk * 4 + l4) ^ (l15 & 7)) << 3)];

    f32x4 acc2[8];
    #pragma unroll
    for (int nf = 0; nf < 8; ++nf) acc2[nf] = (f32x4){0.f,0.f,0.f,0.f};
    const short* w2p = wb + W2P;
    bf16x8 c0[8], c1[8];
    #pragma unroll
    for (int nf = 0; nf < 8; ++nf)
        c0[nf] = *(const bf16x8*)&w2p[((size_t)(0 * 16 + h * 8 + nf)) * 512 + lane * 8];
    #pragma unroll
    for (int nf = 0; nf < 8; ++nf)
        c1[nf] = *(const bf16x8*)&w2p[((size_t)(1 * 16 + h * 8 + nf)) * 512 + lane * 8];
    #pragma unroll
    for (int nf = 0; nf < 8; ++nf)
        acc2[nf] = __builtin_amdgcn_mfma_f32_16x16x32_bf16(a2[0], c0[nf], acc2[nf], 0, 0, 0);
    #pragma unroll
    for (int nf = 0; nf < 8; ++nf)
        c0[nf] = *(const bf16x8*)&w2p[((size_t)(2 * 16 + h * 8 + nf)) * 512 + lane * 8];
    #pragma unroll
    for (int nf = 0; nf < 8; ++nf)
        acc2[nf] = __builtin_amdgcn_mfma_f32_16x16x32_bf16(a2[1], c1[nf], acc2[nf], 0, 0, 0);
    #pragma unroll
    for (int nf = 0; nf < 8; ++nf)
        c1[nf] = *(const bf16x8*)&w2p[((size_t)(3 * 16 + h * 8 + nf)) * 512 + lane * 8];
    #pragma unroll
    for (int nf = 0; nf < 8; ++nf)
        acc2[nf] = __builtin_amdgcn_mfma_f32_16x16x32_bf16(a2[2], c0[nf], acc2[nf], 0, 0, 0);
    #pragma unroll
    for (int nf = 0; nf < 8; ++nf)
        acc2[nf] = __builtin_amdgcn_mfma_f32_16x16x32_bf16(a2[3], c1[nf], acc2[nf], 0, 0, 0);

    // L2 epilogue: bias+relu -> h2 [16][256] (overlay on s_red), own N-half cols
    #pragma unroll
    for (int nf = 0; nf < 8; ++nf) {
        const int c = h * 128 + nf * 16 + l15;
        const float bc = b2v[c];
        #pragma unroll
        for (int i = 0; i < 4; ++i) {
            const int r = l4 * 4 + i;
            const float v = fmaxf(acc2[nf][i] + bc, 0.f);
            s_h2[r * 256 + (((c >> 3) ^ (r & 7)) << 3) + (c & 7)] = f2bf(v);
        }
    }
    __syncthreads();                              // barrier 3: h2 ready

    // ================= Layer 3 + log_softmax (wave 0 only) ====================
    if (!h) {
        const short* w3p = wb + W3P;
        f32x4 acc3 = (f32x4){0.f,0.f,0.f,0.f};
        #pragma unroll
        for (int kt = 0; kt < 8; ++kt) {
            const bf16x8 a3 = *(const bf16x8*)&s_h2[l15 * 256 + (((kt * 4 + l4) ^ (l15 & 7)) << 3)];
            const bf16x8 b3r = *(const bf16x8*)&w3p[(size_t)kt * 512 + lane * 8];
            acc3 = __builtin_amdgcn_mfma_f32_16x16x32_bf16(a3, b3r, acc3, 0, 0, 0);
        }
        const float b3c = (l15 < 10) ? b3v[l15] : 0.f;
        #pragma unroll
        for (int i = 0; i < 4; ++i) {
            const float v = acc3[i] + b3c;
            float m = (l15 < 10) ? v : -1e30f;
            #pragma unroll
            for (int off = 8; off; off >>= 1) m = fmaxf(m, __shfl_xor(m, off, 16));
            const float e = (l15 < 10) ? expf(v - m) : 0.f;
            float sum = e;
            #pragma unroll
            for (int off = 8; off; off >>= 1) sum += __shfl_xor(sum, off, 16);
            const float ls = m + logf(sum);
            if (l15 < 10) {
                const int r = r0 + l4 * 4 + i;
                out[(size_t)r * 10 + l15] = v - ls;
            }
        }
    }
}

extern "C" void kernel_launch(void* const* d_in, const int* in_sizes, int n_in,
                              void* d_out, int out_size, void* d_ws, size_t ws_size,
                              hipStream_t stream) {
    const float* x  = (const float*)d_in[0];
    const float* w1 = (const float*)d_in[1];
    const float* b1 = (const float*)d_in[2];
    const float* w2 = (const float*)d_in[3];
    const float* b2 = (const float*)d_in[4];
    const float* w3 = (const float*)d_in[5];
    const float* b3 = (const float*)d_in[6];
    float* out = (float*)d_out;
    short* wb  = (short*)d_ws;   // needs WTOT*2 = 280KB scratch

    prep_pack<<<(NFRAG_TOT * 64 + TPB - 1) / TPB, TPB, 0, stream>>>(w1, w2, w3, wb);

    dim3 grid(32768 / 16), block(TPB);
    mnist_v5<<<grid, block, 0, stream>>>(x, b1, b2, b3, wb, out);
}

// Round 7
// 38.106 us; speedup vs baseline: 1.4183x; 1.4183x over previous
//
#include <hip/hip_runtime.h>
#include <hip/hip_bf16.h>
#include <math.h>

// v6: single fused kernel (no prep pass), 1 block/CU, weights read once per CU.
//  - 256 blocks x 1024 thr (16 waves: mi=wv>>1 -> 16-row M-tile, nh=wv&1 -> N-half).
//  - Block owns 128 batch rows. x global->reg per wave, 1 K-tile ahead.
//  - L1: 13 K-tiles of 64 (K padded 832); w1 tile [128][64] bf16 double-buffered
//    in LDS, staged via reg fp32->bf16 cvt issued before / written after MFMAs.
//  - L2: 4 K-tiles of 32, w2 [256][32] bf16 dbuf same region. L3: h2/w3 overlay.
//  - 20 barriers total. LDS 72KB. launch_bounds(1024,4) -> <=128 VGPR.

#define TPB 1024

typedef __attribute__((ext_vector_type(8))) short bf16x8;
typedef __attribute__((ext_vector_type(4))) float f32x4;

static __device__ inline short f2bf(float f) {
    union { float f; unsigned u; } v; v.f = f;
    unsigned r = v.u + 0x7fffu + ((v.u >> 16) & 1u);   // RNE
    return (short)(r >> 16);
}
static __device__ inline bf16x8 cvt8(float4 a, float4 b) {
    union { __hip_bfloat162 h2[4]; bf16x8 v; } u;
    u.h2[0] = __float22bfloat162_rn(make_float2(a.x, a.y));
    u.h2[1] = __float22bfloat162_rn(make_float2(a.z, a.w));
    u.h2[2] = __float22bfloat162_rn(make_float2(b.x, b.y));
    u.h2[3] = __float22bfloat162_rn(make_float2(b.z, b.w));
    return u.v;
}
static __device__ inline float4 ld4g(const float* p, bool ok) {
    return ok ? *reinterpret_cast<const float4*>(p) : make_float4(0.f,0.f,0.f,0.f);
}

__global__ __launch_bounds__(TPB, 4) void mnist_v6(
    const float* __restrict__ x,    // [32768,784]
    const float* __restrict__ w1,   // [128,784]
    const float* __restrict__ b1v,  // [128]
    const float* __restrict__ w2,   // [256,128]
    const float* __restrict__ b2v,  // [256]
    const float* __restrict__ w3,   // [10,256]
    const float* __restrict__ b3v,  // [10]
    float* __restrict__ out)        // [32768,10]
{
    __shared__ __align__(16) char smem[72 * 1024];
    short* const s_wt = (short*)smem;               // [2][8192] w-tile dbuf (32KB)
    short* const s_h1 = (short*)(smem + 32 * 1024); // h1 [128][128] bf16 (32KB)
    short* const s_w3 = (short*)(smem + 64 * 1024); // w3 [16][256] bf16 (8KB)
    short* const s_h2 = (short*)smem;               // h2 [128][256] overlay (64KB)

    const int t    = threadIdx.x;
    const int lane = t & 63;
    const int wv   = t >> 6;        // 0..15
    const int mi   = wv >> 1;       // 0..7 -> rows mi*16..+15
    const int nh   = wv & 1;        // N-half
    const int l15  = lane & 15;
    const int l4   = lane >> 4;
    const int r0   = blockIdx.x * 128;

    const int sn = t >> 3, ss = t & 7;   // w1 staging: row 0..127, slot 0..7
    const int un = t >> 2, us = t & 3;   // w2 staging: row 0..255, slot 0..3

    const float* xrow = &x[(size_t)(r0 + mi * 16 + l15) * 784];

    // ---------------- prologue: w1 tile0 -> buf0, x tile0 -> regs --------------
    {
        const float* p = &w1[(size_t)sn * 784 + ss * 8];
        const float4 a = ld4g(p, true), b = ld4g(p + 4, true);
        *(bf16x8*)&s_wt[sn * 64 + ((ss ^ (sn & 7)) << 3)] = cvt8(a, b);
    }
    float4 xc0 = ld4g(xrow + l4 * 8, true);
    float4 xc1 = ld4g(xrow + l4 * 8 + 4, true);
    float4 xc2 = ld4g(xrow + 32 + l4 * 8, true);
    float4 xc3 = ld4g(xrow + 32 + l4 * 8 + 4, true);
    __syncthreads();

    // ---------------- Layer 1: 13 K-tiles of 64 -------------------------------
    f32x4 acc1[4];
    #pragma unroll
    for (int nf = 0; nf < 4; ++nf) acc1[nf] = (f32x4){0.f,0.f,0.f,0.f};

    for (int kt = 0; kt < 13; ++kt) {
        short* const rbuf = s_wt + (kt & 1) * 8192;
        short* const nbuf = s_wt + ((kt & 1) ^ 1) * 8192;
        float4 xn0, xn1, xn2, xn3, wf0, wf1;
        if (kt < 12) {
            // issue next-tile loads FIRST (full-iteration slack for x, MFMA-phase slack for w)
            const int kb = (kt + 1) * 64;
            const int k1 = kb + l4 * 8, k2 = kb + 32 + l4 * 8;
            xn0 = ld4g(xrow + k1, k1 + 8 <= 784);
            xn1 = ld4g(xrow + k1 + 4, k1 + 8 <= 784);
            xn2 = ld4g(xrow + k2, k2 + 8 <= 784);
            xn3 = ld4g(xrow + k2 + 4, k2 + 8 <= 784);
            const int kw = kb + ss * 8;
            const float* p = &w1[(size_t)sn * 784 + kw];
            const bool ok = kw + 8 <= 784;
            wf0 = ld4g(p, ok);
            wf1 = ld4g(p + 4, ok);
        }
        // MFMA phase on current tile
        const bf16x8 a0 = cvt8(xc0, xc1);
        const bf16x8 a1 = cvt8(xc2, xc3);
        #pragma unroll
        for (int nf = 0; nf < 4; ++nf) {
            const int rB = nh * 64 + nf * 16 + l15;
            const bf16x8 b0 = *(const bf16x8*)&rbuf[rB * 64 + (((0 + l4) ^ (rB & 7)) << 3)];
            const bf16x8 b1 = *(const bf16x8*)&rbuf[rB * 64 + (((4 + l4) ^ (rB & 7)) << 3)];
            acc1[nf] = __builtin_amdgcn_mfma_f32_16x16x32_bf16(a0, b0, acc1[nf], 0, 0, 0);
            acc1[nf] = __builtin_amdgcn_mfma_f32_16x16x32_bf16(a1, b1, acc1[nf], 0, 0, 0);
        }
        if (kt < 12) {
            *(bf16x8*)&nbuf[sn * 64 + ((ss ^ (sn & 7)) << 3)] = cvt8(wf0, wf1);
            xc0 = xn0; xc1 = xn1; xc2 = xn2; xc3 = xn3;
        }
        __syncthreads();
    }

    // ---------------- h1 epilogue + stage w2 tile0 + w3 ------------------------
    #pragma unroll
    for (int nf = 0; nf < 4; ++nf) {
        const int c = nh * 64 + nf * 16 + l15;
        const float bc = b1v[c];
        #pragma unroll
        for (int i = 0; i < 4; ++i) {
            const int r = mi * 16 + l4 * 4 + i;
            const float h = fmaxf(acc1[nf][i] + bc, 0.f);
            s_h1[r * 128 + (((c >> 3) ^ (r & 7)) << 3) + (c & 7)] = f2bf(h);
        }
    }
    {
        const float* p = &w2[(size_t)un * 128 + us * 8];
        const float4 wa = ld4g(p, true), wb = ld4g(p + 4, true);
        float4 w3a = make_float4(0,0,0,0), w3b = w3a;
        const int n3 = t >> 5, s3 = t & 31;
        if (t < 512 && n3 < 10) {
            const float* q = &w3[(size_t)n3 * 256 + s3 * 8];
            w3a = ld4g(q, true); w3b = ld4g(q + 4, true);
        }
        *(bf16x8*)&s_wt[8192 + un * 32 + ((us ^ (un & 3)) << 3)] = cvt8(wa, wb);   // tile0 -> buf1
        if (t < 512)
            *(bf16x8*)&s_w3[n3 * 256 + ((s3 ^ (n3 & 7)) << 3)] = cvt8(w3a, w3b);
    }
    __syncthreads();

    // ---------------- Layer 2: 4 K-tiles of 32 --------------------------------
    bf16x8 a2[4];
    {
        const int row = mi * 16 + l15;
        #pragma unroll
        for (int kk = 0; kk < 4; ++kk)
            a2[kk] = *(const bf16x8*)&s_h1[row * 128 + (((kk * 4 + l4) ^ (row & 7)) << 3)];
    }
    f32x4 acc2[8];
    #pragma unroll
    for (int nf = 0; nf < 8; ++nf) acc2[nf] = (f32x4){0.f,0.f,0.f,0.f};

    #pragma unroll
    for (int kt = 0; kt < 4; ++kt) {
        short* const rbuf = s_wt + (((kt + 1) & 1)) * 8192;   // t0->buf1, t1->buf0, ...
        short* const wbuf = s_wt + ((kt & 1)) * 8192;
        float4 wa, wb;
        if (kt < 3) {
            const float* p = &w2[(size_t)un * 128 + (kt + 1) * 32 + us * 8];
            wa = ld4g(p, true); wb = ld4g(p + 4, true);
        }
        #pragma unroll
        for (int nf = 0; nf < 8; ++nf) {
            const int rB = nh * 128 + nf * 16 + l15;
            const bf16x8 b = *(const bf16x8*)&rbuf[rB * 32 + ((l4 ^ (rB & 3)) << 3)];
            acc2[nf] = __builtin_amdgcn_mfma_f32_16x16x32_bf16(a2[kt], b, acc2[nf], 0, 0, 0);
        }
        if (kt < 3)
            *(bf16x8*)&wbuf[un * 32 + ((us ^ (un & 3)) << 3)] = cvt8(wa, wb);
        __syncthreads();
    }

    // ---------------- h2 epilogue (overlay) ------------------------------------
    #pragma unroll
    for (int nf = 0; nf < 8; ++nf) {
        const int c = nh * 128 + nf * 16 + l15;
        const float bc = b2v[c];
        #pragma unroll
        for (int i = 0; i < 4; ++i) {
            const int r = mi * 16 + l4 * 4 + i;
            const float h = fmaxf(acc2[nf][i] + bc, 0.f);
            s_h2[r * 256 + (((c >> 3) ^ (r & 7)) << 3) + (c & 7)] = f2bf(h);
        }
    }
    __syncthreads();

    // ---------------- Layer 3 + log_softmax (nh==0 waves) ----------------------
    if (nh == 0) {
        const int row = mi * 16 + l15;
        f32x4 acc3 = (f32x4){0.f,0.f,0.f,0.f};
        #pragma unroll
        for (int kt = 0; kt < 8; ++kt) {
            const int slot = kt * 4 + l4;
            const bf16x8 a3 = *(const bf16x8*)&s_h2[row * 256 + ((slot ^ (row & 7)) << 3)];
            const bf16x8 b3r = *(const bf16x8*)&s_w3[l15 * 256 + ((slot ^ (l15 & 7)) << 3)];
            acc3 = __builtin_amdgcn_mfma_f32_16x16x32_bf16(a3, b3r, acc3, 0, 0, 0);
        }
        const float b3c = (l15 < 10) ? b3v[l15] : 0.f;
        #pragma unroll
        for (int i = 0; i < 4; ++i) {
            const float v = acc3[i] + b3c;
            float m = (l15 < 10) ? v : -1e30f;
            #pragma unroll
            for (int off = 8; off; off >>= 1) m = fmaxf(m, __shfl_xor(m, off, 16));
            const float e = (l15 < 10) ? expf(v - m) : 0.f;
            float sum = e;
            #pragma unroll
            for (int off = 8; off; off >>= 1) sum += __shfl_xor(sum, off, 16);
            const float ls = m + logf(sum);
            if (l15 < 10) {
                const int r = r0 + mi * 16 + l4 * 4 + i;
                out[(size_t)r * 10 + l15] = v - ls;
            }
        }
    }
}

extern "C" void kernel_launch(void* const* d_in, const int* in_sizes, int n_in,
                              void* d_out, int out_size, void* d_ws, size_t ws_size,
                              hipStream_t stream) {
    const float* x  = (const float*)d_in[0];
    const float* w1 = (const float*)d_in[1];
    const float* b1 = (const float*)d_in[2];
    const float* w2 = (const float*)d_in[3];
    const float* b2 = (const float*)d_in[4];
    const float* w3 = (const float*)d_in[5];
    const float* b3 = (const float*)d_in[6];
    float* out = (float*)d_out;

    dim3 grid(32768 / 128), block(TPB);
    mnist_v6<<<grid, block, 0, stream>>>(x, w1, b1, w2, b2, w3, b3, out);
}